// Round 6
// baseline (150.812 us; speedup 1.0000x reference)
//
#include <hip/hip_runtime.h>
#include <hip/hip_bf16.h>
#include <climits>

#define BATCH   2
#define NPTS    16384   // N
#define NQ      4096    // P
#define CFEAT   64
#define NS      32      // nsample
#define R2      0.01f   // radius^2
#define COUT    (3 + CFEAT)   // 67
#define GDIM    10      // grid cells per axis (cell size = radius)
#define NCELL   (GDIM * GDIM * GDIM)
#define NWORDS  (NPTS / 32)   // 512 words per bitmask

// ---- ws layout (bytes) ----
#define FEATT_BYTES ((size_t)BATCH * NPTS * CFEAT * sizeof(unsigned short))
#define PXYZJ_BYTES ((size_t)BATCH * NPTS * sizeof(float4))
#define OFF_CSTART 0
#define GRID_INTS  (2 * (NCELL + 1))

__device__ __forceinline__ int cell_of(float x, float y, float z) {
    int cx = (int)(x * GDIM); cx = cx < 0 ? 0 : (cx > GDIM - 1 ? GDIM - 1 : cx);
    int cy = (int)(y * GDIM); cy = cy < 0 ? 0 : (cy > GDIM - 1 ? GDIM - 1 : cy);
    int cz = (int)(z * GDIM); cz = cz < 0 ? 0 : (cz > GDIM - 1 ? GDIM - 1 : cz);
    return (cz * GDIM + cy) * GDIM + cx;   // x fastest -> contiguous x-runs
}

__device__ __forceinline__ unsigned short f2bf(float f) {
    unsigned b = __float_as_uint(f);
    return (unsigned short)((b + 0x7FFFu + ((b >> 16) & 1u)) >> 16);   // RNE
}

__device__ __forceinline__ void st_nt(float* p, float v) {
    __builtin_nontemporal_store(v, p);
}

// ============ single prep kernel, role-split blocks (NO grid.sync) ==========
// blocks 0..1   : full grid build for batch b=blockIdx.x, entirely in LDS:
//                 histogram (LDS atomics) -> wave scan -> cstart -> scatter
//                 (replaces memset + prep2; launched first = earliest start)
// blocks 2..513 : feature transpose->bf16 (identical to old prep1)
// LDS: union of tile[64][65] f32 (16640B) and hist/starts (2x4000B).
__global__ __launch_bounds__(256) void prep_all(
    const float* __restrict__ feat, unsigned short* __restrict__ featT16,
    const float* __restrict__ xyz, int* __restrict__ cstart,
    float4* __restrict__ pxyzj)
{
    __shared__ __align__(16) unsigned char smem[64 * 65 * sizeof(float)];
    const int tid = threadIdx.x;

    if (blockIdx.x < 2) {
        // ---------------- grid builder for batch b ----------------
        const int b = blockIdx.x;
        int* hist   = (int*)smem;              // NCELL ints
        int* starts = (int*)smem + NCELL;      // NCELL ints

        for (int i = tid; i < NCELL; i += 256) hist[i] = 0;
        __syncthreads();

        const float* xb = xyz + (size_t)b * NPTS * 3;
        for (int i = tid; i < NPTS; i += 256) {
            const int c = cell_of(xb[i*3], xb[i*3+1], xb[i*3+2]);
            atomicAdd(&hist[c], 1);
        }
        __syncthreads();

        // scan by wave 0: 64 lanes x 16 cells (1024 >= NCELL)
        if (tid < 64) {
            const int lane = tid;
            int c16[16];
            int tot = 0;
            #pragma unroll
            for (int k = 0; k < 16; ++k) {
                const int i = lane * 16 + k;
                c16[k] = (i < NCELL) ? hist[i] : 0;
                tot += c16[k];
            }
            int ex = tot;
            #pragma unroll
            for (int off = 1; off < 64; off <<= 1) {
                const int u = __shfl_up(ex, off);
                if (lane >= off) ex += u;
            }
            ex -= tot;
            int run = ex;
            #pragma unroll
            for (int k = 0; k < 16; ++k) {
                const int i = lane * 16 + k;
                if (i < NCELL) starts[i] = run;
                run += c16[k];
            }
        }
        __syncthreads();

        // cstart (exclusive starts + sentinel)
        int* csb = cstart + b * (NCELL + 1);
        for (int i = tid; i <= NCELL; i += 256)
            csb[i] = (i == NCELL) ? NPTS : starts[i];
        __syncthreads();   // cstart reads of starts[] done before scatter mutates

        // scatter: atomicAdd on starts itself yields the slot index.
        // xyz now L2-hot from the histogram pass.
        float4* pbb = pxyzj + (size_t)b * NPTS;
        for (int i = tid; i < NPTS; i += 256) {
            const float x = xb[i*3], y = xb[i*3+1], z = xb[i*3+2];
            const int c = cell_of(x, y, z);
            const int pos = atomicAdd(&starts[c], 1);
            pbb[pos] = make_float4(x, y, z, __int_as_float(i));
        }
    } else {
        // ---------------- transpose->bf16 (as old prep1) ----------------
        float (*tile)[65] = (float(*)[65])smem;
        const int t    = blockIdx.x - 2;             // 0..511
        const int b    = t >> 8;
        const int n0   = (t & 255) * 64;
        const int lane = tid & 63;
        const int grp  = tid >> 6;                   // 0..3
        const float* fb = feat + (size_t)b * CFEAT * NPTS;
        #pragma unroll
        for (int k = 0; k < 16; ++k) {
            const int c = grp * 16 + k;
            tile[c][lane] = fb[(size_t)c * NPTS + n0 + lane];
        }
        __syncthreads();
        unsigned short* db = featT16 + ((size_t)b * NPTS + n0) * CFEAT;
        #pragma unroll
        for (int k = 0; k < 8; ++k) {
            const int e   = tid + 256 * k;
            const int row = e >> 5;           // 0..63 (point within tile)
            const int c2  = e & 31;           // channel pair
            ushort2 v;
            v.x = f2bf(tile[2 * c2][row]);
            v.y = f2bf(tile[2 * c2 + 1][row]);
            ((ushort2*)(db + (size_t)row * CFEAT))[c2] = v;
        }
    }
}

// ---------------- fused main: ONE WAVE PER QUERY, 4 queries / 256-thr block --
// (byte-identical to R5 — isolating the dispatch-count experiment)
__global__ __launch_bounds__(256, 8) void qg_fused(
    const float* __restrict__ xyz,               // (B, N, 3)
    const float* __restrict__ new_xyz,           // (B, P, 3)
    const int* __restrict__ cstart,              // (B, NCELL+1)
    const float4* __restrict__ pxyzj,            // (B, N) sorted {x,y,z,j}
    const unsigned short* __restrict__ featT16,  // (B, N, C) bf16
    float* __restrict__ out)                     // (B, 67, P, S)
{
    const int tid  = threadIdx.x;       // 0..255
    const int wave = tid >> 6;          // 0..3
    const int lane = tid & 63;
    const int q    = (blockIdx.x << 2) + wave;   // 0..B*P-1
    const int b    = q >> 12;
    const int p    = q & (NQ - 1);

    __shared__ __align__(16) unsigned char smem[4 * 2176];
    unsigned char* wbase = smem + wave * 2176;
    unsigned int* hmask  = (unsigned int*)wbase;        // 512 words
    int* idx_s           = (int*)(wbase + 2048);        // 32 ints

    // zero own bitmask: 64 lanes x 2 uint4 = 2KB
    {
        uint4 z; z.x = 0; z.y = 0; z.z = 0; z.w = 0;
        ((uint4*)hmask)[lane * 2]     = z;
        ((uint4*)hmask)[lane * 2 + 1] = z;
    }

    const float qx = new_xyz[q * 3 + 0];
    const float qy = new_xyz[q * 3 + 1];
    const float qz = new_xyz[q * 3 + 2];
    const float* xb = xyz + (size_t)b * NPTS * 3;
    const int* cs = cstart + b * (NCELL + 1);
    const float4* pb = pxyzj + (size_t)b * NPTS;

    int qcx = (int)(qx * GDIM); qcx = qcx < 0 ? 0 : (qcx > GDIM-1 ? GDIM-1 : qcx);
    int qcy = (int)(qy * GDIM); qcy = qcy < 0 ? 0 : (qcy > GDIM-1 ? GDIM-1 : qcy);
    int qcz = (int)(qz * GDIM); qcz = qcz < 0 ? 0 : (qcz > GDIM-1 ? GDIM-1 : qcz);
    const int x0 = qcx > 0 ? qcx - 1 : 0;
    const int x1 = qcx < GDIM-1 ? qcx + 1 : GDIM-1;
    const int y0 = qcy > 0 ? qcy - 1 : 0;
    const int y1 = qcy < GDIM-1 ? qcy + 1 : GDIM-1;
    const int z0 = qcz > 0 ? qcz - 1 : 0;
    const int z1 = qcz < GDIM-1 ? qcz + 1 : GDIM-1;
    const int ny  = y1 - y0 + 1;                 // 2 or 3
    const int nyz = ny * (z1 - z0 + 1);          // up to 9

    int sv = 0, ev = 0;
    if (lane < nyz) {
        const int gzi = (ny == 3) ? ((lane * 86) >> 8) : (lane >> 1);
        const int gyi = lane - gzi * ny;
        const int crow = ((z0 + gzi) * GDIM + (y0 + gyi)) * GDIM;
        sv = cs[crow + x0];
        ev = cs[crow + x1 + 1];
    }
    __builtin_amdgcn_wave_barrier();    // bitmask zero ordered before atomics

    // ---- compacted scan: dense t-loop; run table in SGPRs ----
    {
        int len = (lane < nyz) ? (ev - sv) : 0;
        int pfx = len;
        #pragma unroll
        for (int off = 1; off < 16; off <<= 1) {
            const int u = __shfl_up(pfx, off);
            if (lane >= off) pfx += u;
        }
        const int T  = __builtin_amdgcn_readfirstlane(__shfl(pfx, 15));
        const int pe = pfx - len;           // exclusive start of this lane's run

        // wave-uniform run table -> SGPRs
        const int b0 = __builtin_amdgcn_readfirstlane(__shfl(sv, 0));
        const int p1 = __builtin_amdgcn_readfirstlane(__shfl(pe, 1));
        const int b1 = __builtin_amdgcn_readfirstlane(__shfl(sv, 1)) - p1;
        const int p2 = __builtin_amdgcn_readfirstlane(__shfl(pe, 2));
        const int b2 = __builtin_amdgcn_readfirstlane(__shfl(sv, 2)) - p2;
        const int p3 = __builtin_amdgcn_readfirstlane(__shfl(pe, 3));
        const int b3 = __builtin_amdgcn_readfirstlane(__shfl(sv, 3)) - p3;
        const int p4 = __builtin_amdgcn_readfirstlane(__shfl(pe, 4));
        const int b4 = __builtin_amdgcn_readfirstlane(__shfl(sv, 4)) - p4;
        const int p5 = __builtin_amdgcn_readfirstlane(__shfl(pe, 5));
        const int b5 = __builtin_amdgcn_readfirstlane(__shfl(sv, 5)) - p5;
        const int p6 = __builtin_amdgcn_readfirstlane(__shfl(pe, 6));
        const int b6 = __builtin_amdgcn_readfirstlane(__shfl(sv, 6)) - p6;
        const int p7 = __builtin_amdgcn_readfirstlane(__shfl(pe, 7));
        const int b7 = __builtin_amdgcn_readfirstlane(__shfl(sv, 7)) - p7;
        const int p8 = __builtin_amdgcn_readfirstlane(__shfl(pe, 8));
        const int b8 = __builtin_amdgcn_readfirstlane(__shfl(sv, 8)) - p8;

        for (int t0 = 0; t0 < T; t0 += 64) {
            const int t = t0 + lane;
            int bsel = b0;
            bsel = (t >= p1) ? b1 : bsel;
            bsel = (t >= p2) ? b2 : bsel;
            bsel = (t >= p3) ? b3 : bsel;
            bsel = (t >= p4) ? b4 : bsel;
            bsel = (t >= p5) ? b5 : bsel;
            bsel = (t >= p6) ? b6 : bsel;
            bsel = (t >= p7) ? b7 : bsel;
            bsel = (t >= p8) ? b8 : bsel;
            const bool valid = t < T;
            const int i = valid ? (bsel + t) : 0;
            const float4 pt = pb[i];            // coalesced dwordx4, L2-resident
            const float dx = pt.x - qx;
            const float dy = pt.y - qy;
            const float dz = pt.z - qz;
            if (valid && (dx*dx + dy*dy + dz*dz < R2)) {
                const int j = __float_as_int(pt.w);
                atomicOr(&hmask[j >> 5], 1u << (j & 31));
            }
        }
    }
    __builtin_amdgcn_wave_barrier();    // all hits landed (same-wave DS order)

    // ---- extraction: once per query (one wave) ----
    int K;
    {
        unsigned int w[8];
        const uint4 a = ((const uint4*)hmask)[lane * 2];
        const uint4 c = ((const uint4*)hmask)[lane * 2 + 1];
        w[0] = a.x; w[1] = a.y; w[2] = a.z; w[3] = a.w;
        w[4] = c.x; w[5] = c.y; w[6] = c.z; w[7] = c.w;

        int cnt8 = 0;
        #pragma unroll
        for (int k = 0; k < 8; ++k) cnt8 += __popc(w[k]);

        int pfx = cnt8;
        #pragma unroll
        for (int off = 1; off < 64; off <<= 1) {
            const int u = __shfl_up(pfx, off);
            if (lane >= off) pfx += u;
        }
        K = __shfl(pfx, 63);
        pfx -= cnt8;

        if (pfx < NS && cnt8 > 0) {
            int r = pfx;
            #pragma unroll
            for (int k = 0; k < 8; ++k) {
                unsigned int m = w[k];
                while (m && r < NS) {
                    const int bit = __builtin_ctz(m);
                    idx_s[r] = lane * 256 + k * 32 + bit;
                    m &= m - 1;
                    ++r;
                }
            }
        }
        __builtin_amdgcn_wave_barrier();
        if (lane < NS && lane >= K) {
            idx_s[lane] = (K > 0) ? idx_s[0] : 0;
        }
        __builtin_amdgcn_wave_barrier();
    }

    // ---- gather + direct NT write, two halves (low register pressure) ----
    const int sm = lane >> 1;           // sample 0..31
    const int h  = lane & 1;            // half-row: 32 channels each
    const int jrow = idx_s[sm];
    const unsigned short* base16 = featT16 +
        ((size_t)b * NPTS + jrow) * CFEAT + (h << 5);

    const size_t cstride = (size_t)NQ * NS;
    const size_t out_q   = ((size_t)b * COUT * NQ + (size_t)p) * NS;

    float xv = 0.f, yv = 0.f, zv = 0.f;
    if (lane < NS) {
        const int j = idx_s[lane];
        xv = xb[j*3+0] - qx;
        yv = xb[j*3+1] - qy;
        zv = xb[j*3+2] - qz;
    }

    const uint4 ga = ((const uint4*)base16)[0];
    const uint4 gb = ((const uint4*)base16)[1];

    if (lane < NS) {
        st_nt(&out[out_q + 0*cstride + lane], xv);
        st_nt(&out[out_q + 1*cstride + lane], yv);
        st_nt(&out[out_q + 2*cstride + lane], zv);
    }

    float* fob = out + out_q + (size_t)(3 + (h << 5)) * cstride + sm;
    #define ST2(kk, u) \
        st_nt(&fob[(size_t)(2*(kk))     * cstride], __uint_as_float((u) << 16)); \
        st_nt(&fob[(size_t)(2*(kk) + 1) * cstride], __uint_as_float((u) & 0xFFFF0000u))

    ST2(0, ga.x); ST2(1, ga.y); ST2(2, ga.z); ST2(3, ga.w);
    ST2(4, gb.x); ST2(5, gb.y); ST2(6, gb.z); ST2(7, gb.w);

    const uint4 gc = ((const uint4*)base16)[2];
    const uint4 gd = ((const uint4*)base16)[3];

    ST2(8,  gc.x); ST2(9,  gc.y); ST2(10, gc.z); ST2(11, gc.w);
    ST2(12, gd.x); ST2(13, gd.y); ST2(14, gd.z); ST2(15, gd.w);
    #undef ST2
}

// ---------------- fallback: linear-scan kernel (fp32 exact) ----------------
__global__ __launch_bounds__(256) void qg_linear(
    const float* __restrict__ xyz, const float* __restrict__ new_xyz,
    const float* __restrict__ feat, float* __restrict__ out)
{
    const int wave = threadIdx.x >> 6;
    const int lane = threadIdx.x & 63;
    const int bp   = blockIdx.x * 4 + wave;
    const int b    = bp >> 12;
    const int p    = bp & (NQ - 1);
    __shared__ int idx_s[4][NS];
    const float qx = new_xyz[bp*3+0], qy = new_xyz[bp*3+1], qz = new_xyz[bp*3+2];
    const float* xb = xyz + (size_t)b * NPTS * 3;
    int cnt = 0;
    const unsigned long long below = (1ull << lane) - 1ull;
    for (int base = 0; base < NPTS; base += 64) {
        const int j = base + lane;
        const float dx = xb[j*3+0]-qx, dy = xb[j*3+1]-qy, dz = xb[j*3+2]-qz;
        const bool hit = dx*dx+dy*dy+dz*dz < R2;
        const unsigned long long m = __ballot(hit);
        if (hit) {
            const int slot = cnt + __popcll(m & below);
            if (slot < NS) idx_s[wave][slot] = j;
        }
        cnt += __popcll(m);
        if (cnt >= NS) break;
    }
    __builtin_amdgcn_wave_barrier();
    if (cnt < NS) {
        const int first = (cnt > 0) ? idx_s[wave][0] : 0;
        if (lane >= cnt && lane < NS) idx_s[wave][lane] = first;
    }
    __builtin_amdgcn_wave_barrier();
    const size_t cstride = (size_t)NQ * NS;
    const size_t out_q = ((size_t)b * COUT * NQ + (size_t)p) * NS;
    if (lane < NS) {
        const int j = idx_s[wave][lane];
        out[out_q + 0*cstride + lane] = xb[j*3+0] - qx;
        out[out_q + 1*cstride + lane] = xb[j*3+1] - qy;
        out[out_q + 2*cstride + lane] = xb[j*3+2] - qz;
    }
    const float* fb = feat + (size_t)b * CFEAT * NPTS;
    const int s = lane & 31, half = lane >> 5;
    const int j = idx_s[wave][s];
    #pragma unroll 8
    for (int c = half; c < CFEAT; c += 2)
        out[out_q + (size_t)(3 + c) * cstride + s] = fb[(size_t)c * NPTS + j];
}

extern "C" void kernel_launch(void* const* d_in, const int* in_sizes, int n_in,
                              void* d_out, int out_size, void* d_ws, size_t ws_size,
                              hipStream_t stream) {
    const float* xyz     = (const float*)d_in[0];  // (2,16384,3)
    const float* new_xyz = (const float*)d_in[1];  // (2,4096,3)
    const float* feat    = (const float*)d_in[2];  // (2,64,16384)
    float* out = (float*)d_out;                    // (2,67,4096,32)

    const size_t need_full = FEATT_BYTES + PXYZJ_BYTES + (size_t)GRID_INTS * sizeof(int);

    if (ws_size >= need_full) {
        unsigned short* featT16 = (unsigned short*)d_ws;
        float4* pxyzj = (float4*)((char*)d_ws + FEATT_BYTES);
        int* cstart = (int*)((char*)d_ws + FEATT_BYTES + PXYZJ_BYTES);

        // 2 nodes total (was 4): no memset (LDS histogram), no prep2
        // (scatter fused into prep_all's builder blocks 0..1).
        prep_all<<<2 + 512, 256, 0, stream>>>(feat, featT16, xyz, cstart, pxyzj);
        qg_fused<<<(BATCH * NQ) / 4, 256, 0, stream>>>(
            xyz, new_xyz, cstart, pxyzj, featT16, out);
    } else {
        qg_linear<<<(BATCH * NQ) / 4, 256, 0, stream>>>(xyz, new_xyz, feat, out);
    }
}

// Round 7
// 140.118 us; speedup vs baseline: 1.0763x; 1.0763x over previous
//
#include <hip/hip_runtime.h>
#include <hip/hip_bf16.h>
#include <climits>

#define BATCH   2
#define NPTS    16384   // N
#define NQ      4096    // P
#define CFEAT   64
#define NS      32      // nsample
#define R2      0.01f   // radius^2
#define COUT    (3 + CFEAT)   // 67
#define GDIM    10      // grid cells per axis (cell size = radius)
#define NCELL   (GDIM * GDIM * GDIM)
#define NSEG    64      // 256-point segments per batch

// ---- ws layout (bytes) ----
// featT16 (B,N,C) bf16 | pxyzj (B,N) float4 | cstart[2*(NCELL+1)] |
// partial[B*NSEG*NCELL] per-segment histograms
#define FEATT_BYTES ((size_t)BATCH * NPTS * CFEAT * sizeof(unsigned short))
#define PXYZJ_BYTES ((size_t)BATCH * NPTS * sizeof(float4))
#define CSTART_INTS (BATCH * (NCELL + 1))
#define PARTIAL_INTS (BATCH * NSEG * NCELL)
#define GRID_INTS  (CSTART_INTS + PARTIAL_INTS)

__device__ __forceinline__ int cell_of(float x, float y, float z) {
    int cx = (int)(x * GDIM); cx = cx < 0 ? 0 : (cx > GDIM - 1 ? GDIM - 1 : cx);
    int cy = (int)(y * GDIM); cy = cy < 0 ? 0 : (cy > GDIM - 1 ? GDIM - 1 : cy);
    int cz = (int)(z * GDIM); cz = cz < 0 ? 0 : (cz > GDIM - 1 ? GDIM - 1 : cz);
    return (cz * GDIM + cy) * GDIM + cx;   // x fastest -> contiguous x-runs
}

__device__ __forceinline__ unsigned short f2bf(float f) {
    unsigned b = __float_as_uint(f);
    return (unsigned short)((b + 0x7FFFu + ((b >> 16) & 1u)) >> 16);   // RNE
}

__device__ __forceinline__ void st_nt(float* p, float v) {
    __builtin_nontemporal_store(v, p);
}

// ------- prep1: transpose->bf16 (blocks 0..511, float4 loads)
//         + per-segment histograms (blocks 512..639, NO global memset needed)
__global__ __launch_bounds__(256) void prep1_kernel(
    const float* __restrict__ feat, unsigned short* __restrict__ featT16,
    const float* __restrict__ xyz, int* __restrict__ partial)
{
    __shared__ __align__(16) unsigned char smem[64 * 65 * sizeof(float)];
    const int tid = threadIdx.x;

    if (blockIdx.x < 512) {
        float (*tile)[65] = (float(*)[65])smem;
        const int b    = blockIdx.x >> 8;
        const int n0   = (blockIdx.x & 255) * 64;
        const int lane = tid & 63;
        const int grp  = tid >> 6;           // 0..3: channels [grp*16, grp*16+16)
        const float* fb = feat + (size_t)b * CFEAT * NPTS;
        const int col4 = (lane & 15) << 2;   // 0,4,..,60
        #pragma unroll
        for (int k = 0; k < 4; ++k) {
            const int c = grp * 16 + k * 4 + (lane >> 4);
            const float4 v = *(const float4*)&fb[(size_t)c * NPTS + n0 + col4];
            tile[c][col4 + 0] = v.x;
            tile[c][col4 + 1] = v.y;
            tile[c][col4 + 2] = v.z;
            tile[c][col4 + 3] = v.w;
        }
        __syncthreads();
        unsigned short* db = featT16 + ((size_t)b * NPTS + n0) * CFEAT;
        #pragma unroll
        for (int k = 0; k < 8; ++k) {
            const int e   = tid + 256 * k;
            const int row = e >> 5;           // 0..63 (point within tile)
            const int c2  = e & 31;           // channel pair
            ushort2 v;
            v.x = f2bf(tile[2 * c2][row]);
            v.y = f2bf(tile[2 * c2 + 1][row]);
            ((ushort2*)(db + (size_t)row * CFEAT))[c2] = v;
        }
    } else {
        // per-segment histogram: block handles 256 points, writes its own
        // partial[] slice non-atomically (every cell written -> no init needed)
        int* hist = (int*)smem;
        const int h   = blockIdx.x - 512;     // 0..127 == b*NSEG+seg
        const int b   = h >> 6;
        const int seg = h & 63;
        for (int i = tid; i < NCELL; i += 256) hist[i] = 0;
        __syncthreads();
        const int j = seg * 256 + tid;        // 0..NPTS-1
        const float* xb = xyz + (size_t)b * NPTS * 3;
        const int c = cell_of(xb[j*3], xb[j*3+1], xb[j*3+2]);
        atomicAdd(&hist[c], 1);
        __syncthreads();
        int* pp = partial + (size_t)h * NCELL;
        for (int i = tid; i < NCELL; i += 256) pp[i] = hist[i];
    }
}

// ------- prep2: totals+block-prefix from partials -> scan -> cstart -> scatter
// 128 blocks x 256 threads, 1 point/thread. No global fill[], no memset.
__global__ __launch_bounds__(256) void prep2_kernel(
    const float* __restrict__ xyz, const int* __restrict__ partial,
    int* __restrict__ cstart, float4* __restrict__ pxyzj)
{
    __shared__ int tot[NCELL];   // totals -> (in-place) exclusive starts
    __shared__ int pfx[NCELL];   // prefix over earlier segments -> write cursor
    const int tid = threadIdx.x;
    const int g   = blockIdx.x;          // 0..127
    const int b   = g >> 6;
    const int gb  = g & 63;              // segment index within batch

    // accumulate totals and own-prefix (coalesced over cells for each h)
    const int* pb = partial + (size_t)b * NSEG * NCELL;
    for (int c = tid; c < NCELL; c += 256) {
        int s = 0, pf = 0;
        for (int h = 0; h < NSEG; ++h) {
            const int v = pb[h * NCELL + c];
            s += v;
            if (h < gb) pf += v;
        }
        tot[c] = s;
        pfx[c] = pf;
    }
    __syncthreads();

    // exclusive scan of tot (wave 0, 16 cells/lane), write back in place
    if (tid < 64) {
        const int lane = tid;
        int c16[16];
        int t = 0;
        #pragma unroll
        for (int k = 0; k < 16; ++k) {
            const int i = lane * 16 + k;
            c16[k] = (i < NCELL) ? tot[i] : 0;
            t += c16[k];
        }
        int ex = t;
        #pragma unroll
        for (int off = 1; off < 64; off <<= 1) {
            const int u = __shfl_up(ex, off);
            if (lane >= off) ex += u;
        }
        ex -= t;
        int run = ex;
        #pragma unroll
        for (int k = 0; k < 16; ++k) {
            const int i = lane * 16 + k;
            if (i < NCELL) tot[i] = run;     // exclusive start
            run += c16[k];
        }
    }
    __syncthreads();

    if (gb == 0) {
        int* csb = cstart + b * (NCELL + 1);
        for (int i = tid; i <= NCELL; i += 256)
            csb[i] = (i == NCELL) ? NPTS : tot[i];
    }

    // write cursor for this block: start + points of earlier segments
    for (int i = tid; i < NCELL; i += 256) pfx[i] += tot[i];
    __syncthreads();

    // scatter: one point per thread; rank among same-cell threads via LDS atomic
    const int j = gb * 256 + tid;
    const float* xb = xyz + (size_t)b * NPTS * 3;
    const float x = xb[j*3], y = xb[j*3+1], z = xb[j*3+2];
    const int c = cell_of(x, y, z);
    const int pos = atomicAdd(&pfx[c], 1);
    pxyzj[(size_t)b * NPTS + pos] = make_float4(x, y, z, __int_as_float(j));
}

// ---------------- fused main: ONE WAVE PER QUERY, 4 queries / 256-thr block --
// (R5 body; launch bound relaxed to plain 256 — forced ",8" was neutral-to-worse)
__global__ __launch_bounds__(256) void qg_fused(
    const float* __restrict__ xyz,               // (B, N, 3)
    const float* __restrict__ new_xyz,           // (B, P, 3)
    const int* __restrict__ cstart,              // (B, NCELL+1)
    const float4* __restrict__ pxyzj,            // (B, N) sorted {x,y,z,j}
    const unsigned short* __restrict__ featT16,  // (B, N, C) bf16
    float* __restrict__ out)                     // (B, 67, P, S)
{
    const int tid  = threadIdx.x;       // 0..255
    const int wave = tid >> 6;          // 0..3
    const int lane = tid & 63;
    const int q    = (blockIdx.x << 2) + wave;   // 0..B*P-1
    const int b    = q >> 12;
    const int p    = q & (NQ - 1);

    __shared__ __align__(16) unsigned char smem[4 * 2176];
    unsigned char* wbase = smem + wave * 2176;
    unsigned int* hmask  = (unsigned int*)wbase;        // 512 words
    int* idx_s           = (int*)(wbase + 2048);        // 32 ints

    // zero own bitmask: 64 lanes x 2 uint4 = 2KB
    {
        uint4 z; z.x = 0; z.y = 0; z.z = 0; z.w = 0;
        ((uint4*)hmask)[lane * 2]     = z;
        ((uint4*)hmask)[lane * 2 + 1] = z;
    }

    const float qx = new_xyz[q * 3 + 0];
    const float qy = new_xyz[q * 3 + 1];
    const float qz = new_xyz[q * 3 + 2];
    const float* xb = xyz + (size_t)b * NPTS * 3;
    const int* cs = cstart + b * (NCELL + 1);
    const float4* pb = pxyzj + (size_t)b * NPTS;

    int qcx = (int)(qx * GDIM); qcx = qcx < 0 ? 0 : (qcx > GDIM-1 ? GDIM-1 : qcx);
    int qcy = (int)(qy * GDIM); qcy = qcy < 0 ? 0 : (qcy > GDIM-1 ? GDIM-1 : qcy);
    int qcz = (int)(qz * GDIM); qcz = qcz < 0 ? 0 : (qcz > GDIM-1 ? GDIM-1 : qcz);
    const int x0 = qcx > 0 ? qcx - 1 : 0;
    const int x1 = qcx < GDIM-1 ? qcx + 1 : GDIM-1;
    const int y0 = qcy > 0 ? qcy - 1 : 0;
    const int y1 = qcy < GDIM-1 ? qcy + 1 : GDIM-1;
    const int z0 = qcz > 0 ? qcz - 1 : 0;
    const int z1 = qcz < GDIM-1 ? qcz + 1 : GDIM-1;
    const int ny  = y1 - y0 + 1;                 // 2 or 3
    const int nyz = ny * (z1 - z0 + 1);          // up to 9

    int sv = 0, ev = 0;
    if (lane < nyz) {
        const int gzi = (ny == 3) ? ((lane * 86) >> 8) : (lane >> 1);
        const int gyi = lane - gzi * ny;
        const int crow = ((z0 + gzi) * GDIM + (y0 + gyi)) * GDIM;
        sv = cs[crow + x0];
        ev = cs[crow + x1 + 1];
    }
    __builtin_amdgcn_wave_barrier();    // bitmask zero ordered before atomics

    // ---- compacted scan: dense t-loop; run table in SGPRs ----
    {
        int len = (lane < nyz) ? (ev - sv) : 0;
        int pfx = len;
        #pragma unroll
        for (int off = 1; off < 16; off <<= 1) {
            const int u = __shfl_up(pfx, off);
            if (lane >= off) pfx += u;
        }
        const int T  = __builtin_amdgcn_readfirstlane(__shfl(pfx, 15));
        const int pe = pfx - len;           // exclusive start of this lane's run

        // wave-uniform run table -> SGPRs
        const int b0 = __builtin_amdgcn_readfirstlane(__shfl(sv, 0));
        const int p1 = __builtin_amdgcn_readfirstlane(__shfl(pe, 1));
        const int b1 = __builtin_amdgcn_readfirstlane(__shfl(sv, 1)) - p1;
        const int p2 = __builtin_amdgcn_readfirstlane(__shfl(pe, 2));
        const int b2 = __builtin_amdgcn_readfirstlane(__shfl(sv, 2)) - p2;
        const int p3 = __builtin_amdgcn_readfirstlane(__shfl(pe, 3));
        const int b3 = __builtin_amdgcn_readfirstlane(__shfl(sv, 3)) - p3;
        const int p4 = __builtin_amdgcn_readfirstlane(__shfl(pe, 4));
        const int b4 = __builtin_amdgcn_readfirstlane(__shfl(sv, 4)) - p4;
        const int p5 = __builtin_amdgcn_readfirstlane(__shfl(pe, 5));
        const int b5 = __builtin_amdgcn_readfirstlane(__shfl(sv, 5)) - p5;
        const int p6 = __builtin_amdgcn_readfirstlane(__shfl(pe, 6));
        const int b6 = __builtin_amdgcn_readfirstlane(__shfl(sv, 6)) - p6;
        const int p7 = __builtin_amdgcn_readfirstlane(__shfl(pe, 7));
        const int b7 = __builtin_amdgcn_readfirstlane(__shfl(sv, 7)) - p7;
        const int p8 = __builtin_amdgcn_readfirstlane(__shfl(pe, 8));
        const int b8 = __builtin_amdgcn_readfirstlane(__shfl(sv, 8)) - p8;

        for (int t0 = 0; t0 < T; t0 += 64) {
            const int t = t0 + lane;
            int bsel = b0;
            bsel = (t >= p1) ? b1 : bsel;
            bsel = (t >= p2) ? b2 : bsel;
            bsel = (t >= p3) ? b3 : bsel;
            bsel = (t >= p4) ? b4 : bsel;
            bsel = (t >= p5) ? b5 : bsel;
            bsel = (t >= p6) ? b6 : bsel;
            bsel = (t >= p7) ? b7 : bsel;
            bsel = (t >= p8) ? b8 : bsel;
            const bool valid = t < T;
            const int i = valid ? (bsel + t) : 0;
            const float4 pt = pb[i];            // coalesced dwordx4, L2-resident
            const float dx = pt.x - qx;
            const float dy = pt.y - qy;
            const float dz = pt.z - qz;
            if (valid && (dx*dx + dy*dy + dz*dz < R2)) {
                const int j = __float_as_int(pt.w);
                atomicOr(&hmask[j >> 5], 1u << (j & 31));
            }
        }
    }
    __builtin_amdgcn_wave_barrier();    // all hits landed (same-wave DS order)

    // ---- extraction: once per query (one wave) ----
    int K;
    {
        unsigned int w[8];
        const uint4 a = ((const uint4*)hmask)[lane * 2];
        const uint4 c = ((const uint4*)hmask)[lane * 2 + 1];
        w[0] = a.x; w[1] = a.y; w[2] = a.z; w[3] = a.w;
        w[4] = c.x; w[5] = c.y; w[6] = c.z; w[7] = c.w;

        int cnt8 = 0;
        #pragma unroll
        for (int k = 0; k < 8; ++k) cnt8 += __popc(w[k]);

        int pfx = cnt8;
        #pragma unroll
        for (int off = 1; off < 64; off <<= 1) {
            const int u = __shfl_up(pfx, off);
            if (lane >= off) pfx += u;
        }
        K = __shfl(pfx, 63);
        pfx -= cnt8;

        if (pfx < NS && cnt8 > 0) {
            int r = pfx;
            #pragma unroll
            for (int k = 0; k < 8; ++k) {
                unsigned int m = w[k];
                while (m && r < NS) {
                    const int bit = __builtin_ctz(m);
                    idx_s[r] = lane * 256 + k * 32 + bit;
                    m &= m - 1;
                    ++r;
                }
            }
        }
        __builtin_amdgcn_wave_barrier();
        if (lane < NS && lane >= K) {
            idx_s[lane] = (K > 0) ? idx_s[0] : 0;
        }
        __builtin_amdgcn_wave_barrier();
    }

    // ---- gather + direct NT write, two halves ----
    const int sm = lane >> 1;           // sample 0..31
    const int h  = lane & 1;            // half-row: 32 channels each
    const int jrow = idx_s[sm];
    const unsigned short* base16 = featT16 +
        ((size_t)b * NPTS + jrow) * CFEAT + (h << 5);

    const size_t cstride = (size_t)NQ * NS;
    const size_t out_q   = ((size_t)b * COUT * NQ + (size_t)p) * NS;

    float xv = 0.f, yv = 0.f, zv = 0.f;
    if (lane < NS) {
        const int j = idx_s[lane];
        xv = xb[j*3+0] - qx;
        yv = xb[j*3+1] - qy;
        zv = xb[j*3+2] - qz;
    }

    const uint4 ga = ((const uint4*)base16)[0];
    const uint4 gb = ((const uint4*)base16)[1];

    if (lane < NS) {
        st_nt(&out[out_q + 0*cstride + lane], xv);
        st_nt(&out[out_q + 1*cstride + lane], yv);
        st_nt(&out[out_q + 2*cstride + lane], zv);
    }

    float* fob = out + out_q + (size_t)(3 + (h << 5)) * cstride + sm;
    #define ST2(kk, u) \
        st_nt(&fob[(size_t)(2*(kk))     * cstride], __uint_as_float((u) << 16)); \
        st_nt(&fob[(size_t)(2*(kk) + 1) * cstride], __uint_as_float((u) & 0xFFFF0000u))

    ST2(0, ga.x); ST2(1, ga.y); ST2(2, ga.z); ST2(3, ga.w);
    ST2(4, gb.x); ST2(5, gb.y); ST2(6, gb.z); ST2(7, gb.w);

    const uint4 gc = ((const uint4*)base16)[2];
    const uint4 gd = ((const uint4*)base16)[3];

    ST2(8,  gc.x); ST2(9,  gc.y); ST2(10, gc.z); ST2(11, gc.w);
    ST2(12, gd.x); ST2(13, gd.y); ST2(14, gd.z); ST2(15, gd.w);
    #undef ST2
}

// ---------------- fallback: linear-scan kernel (fp32 exact) ----------------
__global__ __launch_bounds__(256) void qg_linear(
    const float* __restrict__ xyz, const float* __restrict__ new_xyz,
    const float* __restrict__ feat, float* __restrict__ out)
{
    const int wave = threadIdx.x >> 6;
    const int lane = threadIdx.x & 63;
    const int bp   = blockIdx.x * 4 + wave;
    const int b    = bp >> 12;
    const int p    = bp & (NQ - 1);
    __shared__ int idx_s[4][NS];
    const float qx = new_xyz[bp*3+0], qy = new_xyz[bp*3+1], qz = new_xyz[bp*3+2];
    const float* xb = xyz + (size_t)b * NPTS * 3;
    int cnt = 0;
    const unsigned long long below = (1ull << lane) - 1ull;
    for (int base = 0; base < NPTS; base += 64) {
        const int j = base + lane;
        const float dx = xb[j*3+0]-qx, dy = xb[j*3+1]-qy, dz = xb[j*3+2]-qz;
        const bool hit = dx*dx+dy*dy+dz*dz < R2;
        const unsigned long long m = __ballot(hit);
        if (hit) {
            const int slot = cnt + __popcll(m & below);
            if (slot < NS) idx_s[wave][slot] = j;
        }
        cnt += __popcll(m);
        if (cnt >= NS) break;
    }
    __builtin_amdgcn_wave_barrier();
    if (cnt < NS) {
        const int first = (cnt > 0) ? idx_s[wave][0] : 0;
        if (lane >= cnt && lane < NS) idx_s[wave][lane] = first;
    }
    __builtin_amdgcn_wave_barrier();
    const size_t cstride = (size_t)NQ * NS;
    const size_t out_q = ((size_t)b * COUT * NQ + (size_t)p) * NS;
    if (lane < NS) {
        const int j = idx_s[wave][lane];
        out[out_q + 0*cstride + lane] = xb[j*3+0] - qx;
        out[out_q + 1*cstride + lane] = xb[j*3+1] - qy;
        out[out_q + 2*cstride + lane] = xb[j*3+2] - qz;
    }
    const float* fb = feat + (size_t)b * CFEAT * NPTS;
    const int s = lane & 31, half = lane >> 5;
    const int j = idx_s[wave][s];
    #pragma unroll 8
    for (int c = half; c < CFEAT; c += 2)
        out[out_q + (size_t)(3 + c) * cstride + s] = fb[(size_t)c * NPTS + j];
}

extern "C" void kernel_launch(void* const* d_in, const int* in_sizes, int n_in,
                              void* d_out, int out_size, void* d_ws, size_t ws_size,
                              hipStream_t stream) {
    const float* xyz     = (const float*)d_in[0];  // (2,16384,3)
    const float* new_xyz = (const float*)d_in[1];  // (2,4096,3)
    const float* feat    = (const float*)d_in[2];  // (2,64,16384)
    float* out = (float*)d_out;                    // (2,67,4096,32)

    const size_t need_full = FEATT_BYTES + PXYZJ_BYTES + (size_t)GRID_INTS * sizeof(int);

    if (ws_size >= need_full) {
        unsigned short* featT16 = (unsigned short*)d_ws;
        float4* pxyzj = (float4*)((char*)d_ws + FEATT_BYTES);
        int* gi = (int*)((char*)d_ws + FEATT_BYTES + PXYZJ_BYTES);
        int* cstart  = gi;
        int* partial = gi + CSTART_INTS;

        // 3 nodes (was 4): memset eliminated via per-segment partial histograms.
        prep1_kernel<<<512 + 128, 256, 0, stream>>>(feat, featT16, xyz, partial);
        prep2_kernel<<<128, 256, 0, stream>>>(xyz, partial, cstart, pxyzj);
        qg_fused<<<(BATCH * NQ) / 4, 256, 0, stream>>>(
            xyz, new_xyz, cstart, pxyzj, featT16, out);
    } else {
        qg_linear<<<(BATCH * NQ) / 4, 256, 0, stream>>>(xyz, new_xyz, feat, out);
    }
}

// Round 8
// 108.998 us; speedup vs baseline: 1.3836x; 1.2855x over previous
//
#include <hip/hip_runtime.h>
#include <hip/hip_bf16.h>
#include <climits>

#define BATCH   2
#define NPTS    16384   // N
#define NQ      4096    // P
#define CFEAT   64
#define NS      32      // nsample
#define R2      0.01f   // radius^2
#define COUT    (3 + CFEAT)   // 67
#define GDIM    10      // grid cells per axis (cell size = radius)
#define NCELL   (GDIM * GDIM * GDIM)
#define NWORDS  (NPTS / 32)   // 512 words per bitmask

// ---- ws layout (bytes) ----
#define FEATT_BYTES ((size_t)BATCH * NPTS * CFEAT * sizeof(unsigned short))
#define PXYZJ_BYTES ((size_t)BATCH * NPTS * sizeof(float4))
#define OFF_CNT    0
#define OFF_FILL   (2 * NCELL)
#define OFF_CSTART (4 * NCELL)
#define GRID_INTS  (4 * NCELL + 2 * (NCELL + 1))

__device__ __forceinline__ int cell_of(float x, float y, float z) {
    int cx = (int)(x * GDIM); cx = cx < 0 ? 0 : (cx > GDIM - 1 ? GDIM - 1 : cx);
    int cy = (int)(y * GDIM); cy = cy < 0 ? 0 : (cy > GDIM - 1 ? GDIM - 1 : cy);
    int cz = (int)(z * GDIM); cz = cz < 0 ? 0 : (cz > GDIM - 1 ? GDIM - 1 : cz);
    return (cz * GDIM + cy) * GDIM + cx;   // x fastest -> contiguous x-runs
}

__device__ __forceinline__ unsigned short f2bf(float f) {
    unsigned b = __float_as_uint(f);
    return (unsigned short)((b + 0x7FFFu + ((b >> 16) & 1u)) >> 16);   // RNE
}

// ------- fused: transpose->bf16 (blocks 0..511) + count (blocks 512..639) ----
__global__ __launch_bounds__(256) void prep1_kernel(
    const float* __restrict__ feat, unsigned short* __restrict__ featT16,
    const float* __restrict__ xyz, int* __restrict__ cnt)
{
    __shared__ float tile[64][65];
    if (blockIdx.x < 512) {
        const int b    = blockIdx.x >> 8;
        const int n0   = (blockIdx.x & 255) * 64;
        const int lane = threadIdx.x & 63;
        const int grp  = threadIdx.x >> 6;           // 0..3
        const float* fb = feat + (size_t)b * CFEAT * NPTS;
        #pragma unroll
        for (int k = 0; k < 16; ++k) {
            const int c = grp * 16 + k;
            tile[c][lane] = fb[(size_t)c * NPTS + n0 + lane];
        }
        __syncthreads();
        unsigned short* db = featT16 + ((size_t)b * NPTS + n0) * CFEAT;
        #pragma unroll
        for (int k = 0; k < 8; ++k) {
            const int e   = threadIdx.x + 256 * k;
            const int row = e >> 5;           // 0..63 (point within tile)
            const int c2  = e & 31;           // channel pair
            ushort2 v;
            v.x = f2bf(tile[2 * c2][row]);
            v.y = f2bf(tile[2 * c2 + 1][row]);
            ((ushort2*)(db + (size_t)row * CFEAT))[c2] = v;
        }
    } else {
        const int g = (blockIdx.x - 512) * 256 + threadIdx.x;   // 0..B*N-1
        const int b = g >> 14;
        const int c = cell_of(xyz[g*3], xyz[g*3+1], xyz[g*3+2]);
        atomicAdd(&cnt[b * NCELL + c], 1);
    }
}

// ---------------- scan (redundant per block, in LDS) + scatter ----------------
__global__ __launch_bounds__(256) void prep2_kernel(
    const float* __restrict__ xyz, const int* __restrict__ cnt,
    int* __restrict__ fill, int* __restrict__ cstart,
    float4* __restrict__ pxyzj)
{
    __shared__ int scs[2 * NCELL];       // exclusive starts, both batches
    const int tid  = threadIdx.x;
    const int lane = tid & 63;

    if (tid < 128) {
        const int b = tid >> 6;
        int c16[16];
        int tot = 0;
        #pragma unroll
        for (int k = 0; k < 16; ++k) {
            const int i = lane * 16 + k;
            c16[k] = (i < NCELL) ? cnt[b * NCELL + i] : 0;
            tot += c16[k];
        }
        int ex = tot;
        #pragma unroll
        for (int off = 1; off < 64; off <<= 1) {
            const int u = __shfl_up(ex, off);
            if (lane >= off) ex += u;
        }
        ex -= tot;
        int run = ex;
        #pragma unroll
        for (int k = 0; k < 16; ++k) {
            const int i = lane * 16 + k;
            if (i < NCELL) scs[b * NCELL + i] = run;
            run += c16[k];
        }
    }
    __syncthreads();

    if (blockIdx.x == 0) {
        for (int i = tid; i < 2 * (NCELL + 1); i += 256) {
            const int b  = i / (NCELL + 1);
            const int ci = i - b * (NCELL + 1);
            cstart[i] = (ci == NCELL) ? NPTS : scs[b * NCELL + ci];
        }
    }

    const int g = blockIdx.x * 256 + tid;
    const int b = g >> 14;
    const int j = g & (NPTS - 1);
    const float x = xyz[g*3], y = xyz[g*3+1], z = xyz[g*3+2];
    const int c = cell_of(x, y, z);
    const int pos = atomicAdd(&fill[b * NCELL + c], 1);
    pxyzj[b * NPTS + scs[b * NCELL + c] + pos] =
        make_float4(x, y, z, __int_as_float(j));
}

// ---------------- fused main: ONE WAVE PER QUERY, 4 queries / 256-thr block --
// R8: R1 body + XCD-aware block swizzle (T1). Default dispatch round-robins
// consecutive blocks (adjacent 128B output lines in every channel plane)
// across the 8 XCD L2s -> writeback streams to DRAM are interleaved at page
// granularity. Swizzle gives each XCD a contiguous 1024-query range so each
// L2's writeback is contiguous (128KB runs per channel plane).
__global__ __launch_bounds__(256) void qg_fused(
    const float* __restrict__ xyz,               // (B, N, 3)
    const float* __restrict__ new_xyz,           // (B, P, 3)
    const int* __restrict__ cstart,              // (B, NCELL+1)
    const float4* __restrict__ pxyzj,            // (B, N) sorted {x,y,z,j}
    const unsigned short* __restrict__ featT16,  // (B, N, C) bf16
    float* __restrict__ out)                     // (B, 67, P, S)
{
    const int tid  = threadIdx.x;       // 0..255
    const int wave = tid >> 6;          // 0..3
    const int lane = tid & 63;
    // XCD swizzle: grid = 2048 blocks, 8 XCDs, 2048 % 8 == 0 -> bijective.
    // HW places block bid on XCD (bid % 8); give that XCD work chunk
    // (bid % 8)*256 + bid/8  ->  XCD x owns contiguous queries [x*1024, x*1024+1024).
    const int swz  = ((blockIdx.x & 7) << 8) + (blockIdx.x >> 3);
    const int q    = (swz << 2) + wave;          // 0..B*P-1
    const int b    = q >> 12;
    const int p    = q & (NQ - 1);

    __shared__ __align__(16) unsigned char smem[4 * 2176];
    unsigned char* wbase = smem + wave * 2176;
    unsigned int* hmask  = (unsigned int*)wbase;        // 512 words
    int* idx_s           = (int*)(wbase + 2048);        // 32 ints

    // zero own bitmask: 64 lanes x 2 uint4 = 2KB
    {
        uint4 z; z.x = 0; z.y = 0; z.z = 0; z.w = 0;
        ((uint4*)hmask)[lane * 2]     = z;
        ((uint4*)hmask)[lane * 2 + 1] = z;
    }

    const float qx = new_xyz[q * 3 + 0];
    const float qy = new_xyz[q * 3 + 1];
    const float qz = new_xyz[q * 3 + 2];
    const float* xb = xyz + (size_t)b * NPTS * 3;
    const int* cs = cstart + b * (NCELL + 1);
    const float4* pb = pxyzj + (size_t)b * NPTS;

    int qcx = (int)(qx * GDIM); qcx = qcx < 0 ? 0 : (qcx > GDIM-1 ? GDIM-1 : qcx);
    int qcy = (int)(qy * GDIM); qcy = qcy < 0 ? 0 : (qcy > GDIM-1 ? GDIM-1 : qcy);
    int qcz = (int)(qz * GDIM); qcz = qcz < 0 ? 0 : (qcz > GDIM-1 ? GDIM-1 : qcz);
    const int x0 = qcx > 0 ? qcx - 1 : 0;
    const int x1 = qcx < GDIM-1 ? qcx + 1 : GDIM-1;
    const int y0 = qcy > 0 ? qcy - 1 : 0;
    const int y1 = qcy < GDIM-1 ? qcy + 1 : GDIM-1;
    const int z0 = qcz > 0 ? qcz - 1 : 0;
    const int z1 = qcz < GDIM-1 ? qcz + 1 : GDIM-1;
    const int ny  = y1 - y0 + 1;                 // 2 or 3
    const int nyz = ny * (z1 - z0 + 1);          // up to 9

    int sv = 0, ev = 0;
    if (lane < nyz) {
        const int gzi = (ny == 3) ? ((lane * 86) >> 8) : (lane >> 1);
        const int gyi = lane - gzi * ny;
        const int crow = ((z0 + gzi) * GDIM + (y0 + gyi)) * GDIM;
        sv = cs[crow + x0];
        ev = cs[crow + x1 + 1];
    }
    __builtin_amdgcn_wave_barrier();    // bitmask zero ordered before atomics

    for (int r = 0; r < nyz; ++r) {
        const int s = __shfl(sv, r);
        const int e = __shfl(ev, r);
        for (int pos = s; pos < e; pos += 64) {
            const int i = pos + lane;
            const bool inr = i < e;
            const float4 pt = pb[inr ? i : 0];   // coalesced dwordx4
            const float dx = pt.x - qx;
            const float dy = pt.y - qy;
            const float dz = pt.z - qz;
            if (inr && (dx*dx + dy*dy + dz*dz < R2)) {
                const int j = __float_as_int(pt.w);
                atomicOr(&hmask[j >> 5], 1u << (j & 31));
            }
        }
    }
    __builtin_amdgcn_wave_barrier();    // all hits landed (same-wave DS order)

    // ---- extraction: once per query (one wave) ----
    int K;
    {
        unsigned int w[8];
        const uint4 a = ((const uint4*)hmask)[lane * 2];
        const uint4 c = ((const uint4*)hmask)[lane * 2 + 1];
        w[0] = a.x; w[1] = a.y; w[2] = a.z; w[3] = a.w;
        w[4] = c.x; w[5] = c.y; w[6] = c.z; w[7] = c.w;

        int cnt8 = 0;
        #pragma unroll
        for (int k = 0; k < 8; ++k) cnt8 += __popc(w[k]);

        int pfx = cnt8;
        #pragma unroll
        for (int off = 1; off < 64; off <<= 1) {
            const int u = __shfl_up(pfx, off);
            if (lane >= off) pfx += u;
        }
        K = __shfl(pfx, 63);
        pfx -= cnt8;

        if (pfx < NS && cnt8 > 0) {
            int r = pfx;
            #pragma unroll
            for (int k = 0; k < 8; ++k) {
                unsigned int m = w[k];
                while (m && r < NS) {
                    const int bit = __builtin_ctz(m);
                    idx_s[r] = lane * 256 + k * 32 + bit;
                    m &= m - 1;
                    ++r;
                }
            }
        }
        __builtin_amdgcn_wave_barrier();
        if (lane < NS && lane >= K) {
            idx_s[lane] = (K > 0) ? idx_s[0] : 0;
        }
        __builtin_amdgcn_wave_barrier();
    }

    // ---- gather + direct write (no LDS tile) ----
    const int sm = lane >> 1;           // sample 0..31
    const int h  = lane & 1;            // half-row: 32 channels each
    const int jrow = idx_s[sm];
    const uint4* bptr = (const uint4*)(featT16 +
        ((size_t)b * NPTS + jrow) * CFEAT + (h << 5));
    const uint4 ga = bptr[0];
    const uint4 gb = bptr[1];
    const uint4 gc = bptr[2];
    const uint4 gd = bptr[3];

    const size_t cstride = (size_t)NQ * NS;
    const size_t out_q   = ((size_t)b * COUT * NQ + (size_t)p) * NS;

    if (lane < NS) {
        const int j = idx_s[lane];
        out[out_q + 0*cstride + lane] = xb[j*3+0] - qx;
        out[out_q + 1*cstride + lane] = xb[j*3+1] - qy;
        out[out_q + 2*cstride + lane] = xb[j*3+2] - qz;
    }

    // lane (sm,h) holds 32 channels (16 dwords) of sample sm.
    float* fob = out + out_q + (size_t)(3 + (h << 5)) * cstride + sm;
    const unsigned comps[16] = {ga.x, ga.y, ga.z, ga.w,
                                gb.x, gb.y, gb.z, gb.w,
                                gc.x, gc.y, gc.z, gc.w,
                                gd.x, gd.y, gd.z, gd.w};
    #pragma unroll
    for (int kk = 0; kk < 16; ++kk) {
        const unsigned u = comps[kk];
        fob[(size_t)(2*kk)     * cstride] = __uint_as_float(u << 16);          // even ch
        fob[(size_t)(2*kk + 1) * cstride] = __uint_as_float(u & 0xFFFF0000u);  // odd ch
    }
}

// ---------------- fallback: linear-scan kernel (fp32 exact) ----------------
__global__ __launch_bounds__(256) void qg_linear(
    const float* __restrict__ xyz, const float* __restrict__ new_xyz,
    const float* __restrict__ feat, float* __restrict__ out)
{
    const int wave = threadIdx.x >> 6;
    const int lane = threadIdx.x & 63;
    const int bp   = blockIdx.x * 4 + wave;
    const int b    = bp >> 12;
    const int p    = bp & (NQ - 1);
    __shared__ int idx_s[4][NS];
    const float qx = new_xyz[bp*3+0], qy = new_xyz[bp*3+1], qz = new_xyz[bp*3+2];
    const float* xb = xyz + (size_t)b * NPTS * 3;
    int cnt = 0;
    const unsigned long long below = (1ull << lane) - 1ull;
    for (int base = 0; base < NPTS; base += 64) {
        const int j = base + lane;
        const float dx = xb[j*3+0]-qx, dy = xb[j*3+1]-qy, dz = xb[j*3+2]-qz;
        const bool hit = dx*dx+dy*dy+dz*dz < R2;
        const unsigned long long m = __ballot(hit);
        if (hit) {
            const int slot = cnt + __popcll(m & below);
            if (slot < NS) idx_s[wave][slot] = j;
        }
        cnt += __popcll(m);
        if (cnt >= NS) break;
    }
    __builtin_amdgcn_wave_barrier();
    if (cnt < NS) {
        const int first = (cnt > 0) ? idx_s[wave][0] : 0;
        if (lane >= cnt && lane < NS) idx_s[wave][lane] = first;
    }
    __builtin_amdgcn_wave_barrier();
    const size_t cstride = (size_t)NQ * NS;
    const size_t out_q = ((size_t)b * COUT * NQ + (size_t)p) * NS;
    if (lane < NS) {
        const int j = idx_s[wave][lane];
        out[out_q + 0*cstride + lane] = xb[j*3+0] - qx;
        out[out_q + 1*cstride + lane] = xb[j*3+1] - qy;
        out[out_q + 2*cstride + lane] = xb[j*3+2] - qz;
    }
    const float* fb = feat + (size_t)b * CFEAT * NPTS;
    const int s = lane & 31, half = lane >> 5;
    const int j = idx_s[wave][s];
    #pragma unroll 8
    for (int c = half; c < CFEAT; c += 2)
        out[out_q + (size_t)(3 + c) * cstride + s] = fb[(size_t)c * NPTS + j];
}

extern "C" void kernel_launch(void* const* d_in, const int* in_sizes, int n_in,
                              void* d_out, int out_size, void* d_ws, size_t ws_size,
                              hipStream_t stream) {
    const float* xyz     = (const float*)d_in[0];  // (2,16384,3)
    const float* new_xyz = (const float*)d_in[1];  // (2,4096,3)
    const float* feat    = (const float*)d_in[2];  // (2,64,16384)
    float* out = (float*)d_out;                    // (2,67,4096,32)

    const size_t need_full = FEATT_BYTES + PXYZJ_BYTES + (size_t)GRID_INTS * sizeof(int);

    if (ws_size >= need_full) {
        unsigned short* featT16 = (unsigned short*)d_ws;
        float4* pxyzj = (float4*)((char*)d_ws + FEATT_BYTES);
        int* gi = (int*)((char*)d_ws + FEATT_BYTES + PXYZJ_BYTES);
        int* cnt    = gi + OFF_CNT;
        int* fill   = gi + OFF_FILL;
        int* cstart = gi + OFF_CSTART;

        hipMemsetAsync(cnt, 0, 4 * NCELL * sizeof(int), stream);  // cnt + fill
        prep1_kernel<<<512 + (BATCH * NPTS) / 256, 256, 0, stream>>>(feat, featT16, xyz, cnt);
        prep2_kernel<<<(BATCH * NPTS) / 256, 256, 0, stream>>>(xyz, cnt, fill, cstart, pxyzj);
        qg_fused<<<(BATCH * NQ) / 4, 256, 0, stream>>>(
            xyz, new_xyz, cstart, pxyzj, featT16, out);
    } else {
        qg_linear<<<(BATCH * NQ) / 4, 256, 0, stream>>>(xyz, new_xyz, feat, out);
    }
}